// Round 8
// baseline (296.510 us; speedup 1.0000x reference)
//
#include <hip/hip_runtime.h>
#include <math.h>

// Cross-bilateral filter, B=4, C=3, H=720, W=1280, WIN=11 (pad=5), f32.
//
// R8: all-f32 DOT-FORM weights + one flat uniform loop.
//  - Per cell store u = sqrt(2*log2e/sigma)*v (7 channels f32, two float4s;
//    slot 8 = gg = 0.5*u.u, f32). Per tap:
//      s = u_t . u_p - gg_t - gg_p   (<= 0, exact to ~1e-4 in f32)
//      w = exp2(s)
//    13 plain f32 slots per tap-pixel: 1 sub + 7 fma + exp + 3 fma + 1 add.
//    (R4's dot-form failure was f16-stored gg, not the algebra: here gg and
//    all channels are f32, so s == -||u_t-u_p||^2 up to f32 roundoff.)
//  - OUT-OF-WINDOW taps are killed arithmetically: per row t and pixel k,
//    seed_k = (active ? -gg_pk : -1e30f); w = exp2(-1e30 + ...) == 0.
//    -> single uniform 14-row x 11-dx loop, no ramp sections, no branches.
//  - dx loop ROLLED (#pragma unroll 1) with 1-ahead named prefetch: bounds
//    register pressure (R6/R7's spills came from 11-cell unrolled bursts:
//    WRITE_SIZE 334MB vs 43MB output).
//  - Input rgb as f16 uint2; converted to f32 ONCE per cell (shared by 4 px).
//  - 4 vertically adjacent px/thread, 32x32 tile. LDS 42*42*40B = 70.6 KB
//    -> 2 blocks/CU.

#define HH   720
#define WW   1280
#define PAD  5
#define WIN  11
#define TW   32
#define TH   32
#define HW2  42            // halo dim = TW + 2*PAD

typedef _Float16 h2 __attribute__((ext_vector_type(2)));

__device__ __forceinline__ unsigned pk2(float a, float b) {
    unsigned lo = __builtin_bit_cast(unsigned short, (_Float16)a);
    unsigned hi = __builtin_bit_cast(unsigned short, (_Float16)b);
    return lo | (hi << 16);
}
__device__ __forceinline__ h2 bch2(unsigned u) { return __builtin_bit_cast(h2, u); }

__global__ __launch_bounds__(256, 2)
void xbilateral_kernel(const float* __restrict__ inp,
                       const float* __restrict__ alb,
                       const float* __restrict__ nrm,
                       const float* __restrict__ dep,
                       float* __restrict__ out)
{
    __shared__ float4 sGA[HW2][HW2];  // {a0,a1,a2,dep} * sqrt(2*log2e/sigma)
    __shared__ float4 sGB[HW2][HW2];  // {n0,n1,n2, gg}  (gg = 0.5*u.u, f32)
    __shared__ uint2  sI [HW2][HW2];  // f16 {i0,i1, i2,1}

    const int tid = threadIdx.x;
    const int lx  = tid & 31;        // 0..31
    const int ly  = tid >> 5;        // 0..7
    const int bx0 = blockIdx.x * TW;
    const int by0 = blockIdx.y * TH;
    const int b   = blockIdx.z;

    const float kA2 = 16.98653137f;  // sqrt(2*1.44269504/0.01)
    const float kN2 = 5.37154913f;   // sqrt(2*1.44269504/0.1)

    const size_t plane = (size_t)HH * WW;
    const float* albB = alb + (size_t)b * 3 * plane;
    const float* nrmB = nrm + (size_t)b * 3 * plane;
    const float* inpB = inp + (size_t)b * 3 * plane;
    const float* depB = dep + (size_t)b * plane;

    // ---- stage halo tile (clamped coords, sqrt2*k-scaled f32, gg f32) ----
    for (int idx = tid; idx < HW2 * HW2; idx += 256) {
        int r = idx / HW2;
        int c = idx - r * HW2;
        int gy = by0 + r - PAD; gy = min(max(gy, 0), HH - 1);
        int gx = bx0 + c - PAD; gx = min(max(gx, 0), WW - 1);
        size_t o = (size_t)gy * WW + gx;
        float a0 = albB[o] * kA2, a1 = albB[plane + o] * kA2, a2 = albB[2 * plane + o] * kA2;
        float n0 = nrmB[o] * kN2, n1 = nrmB[plane + o] * kN2, n2 = nrmB[2 * plane + o] * kN2;
        float d0 = depB[o] * kN2;
        float gg = 0.5f * (a0 * a0 + a1 * a1 + a2 * a2 + d0 * d0 +
                           n0 * n0 + n1 * n1 + n2 * n2);
        sGA[r][c] = make_float4(a0, a1, a2, d0);
        sGB[r][c] = make_float4(n0, n1, n2, gg);
        float i0 = inpB[o], i1 = inpB[plane + o], i2 = inpB[2 * plane + o];
        sI[r][c] = make_uint2(pk2(i0, i1), pk2(i2, 1.f));
    }
    __syncthreads();

    // ---- per-thread: 4 vertically adjacent pixels, tile rows 4*ly + 0..3 ----
    const int py0 = 4 * ly;

    // centers (already scaled); bneg = -gg_p
    float4 cA0 = sGA[py0 + 0 + PAD][lx + PAD], cB0 = sGB[py0 + 0 + PAD][lx + PAD];
    float4 cA1 = sGA[py0 + 1 + PAD][lx + PAD], cB1 = sGB[py0 + 1 + PAD][lx + PAD];
    float4 cA2 = sGA[py0 + 2 + PAD][lx + PAD], cB2 = sGB[py0 + 2 + PAD][lx + PAD];
    float4 cA3 = sGA[py0 + 3 + PAD][lx + PAD], cB3 = sGB[py0 + 3 + PAD][lx + PAD];
    float bn0 = -cB0.w, bn1 = -cB1.w, bn2 = -cB2.w, bn3 = -cB3.w;

    float4 a0 = make_float4(0.f, 0.f, 0.f, 0.f);
    float4 a1 = make_float4(0.f, 0.f, 0.f, 0.f);
    float4 a2 = make_float4(0.f, 0.f, 0.f, 0.f);
    float4 a3 = make_float4(0.f, 0.f, 0.f, 0.f);

    const float KILL = -1e30f;

#pragma unroll 1
    for (int t = 0; t < 14; ++t) {                 // window rows
        // per-row seeds: kill out-of-window pixels arithmetically (w -> 0)
        float bk0 = ((unsigned)(t - 0) <= 10u) ? bn0 : KILL;
        float bk1 = ((unsigned)(t - 1) <= 10u) ? bn1 : KILL;
        float bk2 = ((unsigned)(t - 2) <= 10u) ? bn2 : KILL;
        float bk3 = ((unsigned)(t - 3) <= 10u) ? bn3 : KILL;

        const float4* pA = &sGA[py0 + t][lx];
        const float4* pB = &sGB[py0 + t][lx];
        const uint2*  pI = &sI [py0 + t][lx];

        float4 ga = pA[0], gb = pB[0];
        uint2  ti = pI[0];

#pragma unroll 1
        for (int dx = 0; dx < WIN; ++dx) {
            int nx = dx + 1; nx = (nx > WIN - 1) ? (WIN - 1) : nx;
            float4 gan = pA[nx], gbn = pB[nx];     // 1-ahead prefetch (named)
            uint2  tin = pI[nx];

            h2 lo = bch2(ti.x), hi = bch2(ti.y);
            float i0 = (float)lo.x, i1 = (float)lo.y, i2 = (float)hi.x;
            float ggt = gb.w;

#define TAP(K)                                                                  \
            {                                                                   \
                float s = fmaf(ga.x, cA##K.x, fmaf(ga.y, cA##K.y,               \
                          fmaf(ga.z, cA##K.z, fmaf(ga.w, cA##K.w,               \
                          fmaf(gb.x, cB##K.x, fmaf(gb.y, cB##K.y,               \
                          fmaf(gb.z, cB##K.z, bk##K - ggt)))))));               \
                float w = __builtin_amdgcn_exp2f(s);                            \
                a##K.x = fmaf(w, i0, a##K.x);                                   \
                a##K.y = fmaf(w, i1, a##K.y);                                   \
                a##K.z = fmaf(w, i2, a##K.z);                                   \
                a##K.w += w;                                                    \
            }
            TAP(0) TAP(1) TAP(2) TAP(3)
#undef TAP
            ga = gan; gb = gbn; ti = tin;
        }
    }

    // ---- write out (guard H tail: grid y = ceil(720/32) = 23) ----
    const int ox = bx0 + lx;
    float* outB = out + (size_t)b * 3 * plane;
#define WOUT(K)                                                                 \
    {                                                                           \
        int oy = by0 + py0 + K;                                                 \
        if (oy < HH) {                                                          \
            float inv = 1.0f / fmaxf(a##K.w, 1e-10f);                           \
            size_t o = (size_t)oy * WW + ox;                                    \
            outB[o]             = a##K.x * inv;                                 \
            outB[plane + o]     = a##K.y * inv;                                 \
            outB[2 * plane + o] = a##K.z * inv;                                 \
        }                                                                       \
    }
    WOUT(0) WOUT(1) WOUT(2) WOUT(3)
#undef WOUT
}

extern "C" void kernel_launch(void* const* d_in, const int* in_sizes, int n_in,
                              void* d_out, int out_size, void* d_ws, size_t ws_size,
                              hipStream_t stream) {
    const float* inp = (const float*)d_in[0];
    const float* alb = (const float*)d_in[1];
    const float* nrm = (const float*)d_in[2];
    const float* dep = (const float*)d_in[3];
    // d_in[4] = win_size (always 11, compiled in)
    float* out = (float*)d_out;

    dim3 grid(WW / TW, (HH + TH - 1) / TH, 4);   // 40 x 23 x 4
    dim3 block(256);
    xbilateral_kernel<<<grid, block, 0, stream>>>(inp, alb, nrm, dep, out);
}

// Round 9
// 284.604 us; speedup vs baseline: 1.0418x; 1.0418x over previous
//
#include <hip/hip_runtime.h>
#include <math.h>

// Cross-bilateral filter, B=4, C=3, H=720, W=1280, WIN=11 (pad=5), f32.
//
// R9: hierarchical tap CULLING (weight-aware early-out).
//  - Phase 1 (every tap): albedo+depth partial distance e_AD in f32 via
//    2 pk_sub + 2 v_dot2_f32_f16 per pixel, seeded with a kill constant
//    (+1e4) for out-of-window pixels (replaces all ramp logic). f32 min
//    over the thread's 4 pixels, then ONE wave-uniform branch:
//    if (__any(min < 40)) -> phase 2. For this input distribution
//    P(alive) ~ 3e-4/tap-px -> ~7% of wave-iterations enter phase 2.
//  - Phase 2 (rare): read normals + input cells (b64 each), finish
//    e = e_AD + e_N, w = exp2(-e), accumulate rgb+wsum via v_fma_mix
//    (input stored {i0,i1,i2,1.0} f16 -> wsum is the 4th fma_mix).
//  - Culled taps have true w < 2^-40; dropping them changes the output by
//    < 1e-10 relative (center tap always survives with w=1). Smooth inputs
//    just run phase 2 always (correct, ~baseline speed).
//  - dx fully unrolled (immediate ds_read offsets, no pointer rotation);
//    all hot values are named scalars (R6/R7 scratch lesson).
//  - LDS: 3 x uint2[42][42] = 42.3 KB -> 3 blocks/CU.

#define HH   720
#define WW   1280
#define PAD  5
#define WIN  11
#define TW   32
#define TH   32
#define HW2  42            // halo dim = TW + 2*PAD

#define T_CULL 40.0f       // log2-domain cutoff: w < 2^-40 ~ 9e-13
#define BIGE   1.0e4f      // kill constant for out-of-window pixels

typedef _Float16 h2 __attribute__((ext_vector_type(2)));

__device__ __forceinline__ unsigned pk2(float a, float b) {
    unsigned lo = __builtin_bit_cast(unsigned short, (_Float16)a);
    unsigned hi = __builtin_bit_cast(unsigned short, (_Float16)b);
    return lo | (hi << 16);
}
__device__ __forceinline__ h2 bch2(unsigned u) { return __builtin_bit_cast(h2, u); }

__device__ __forceinline__ float fdot2(h2 a, h2 b, float c) {
#if __has_builtin(__builtin_amdgcn_fdot2)
    return __builtin_amdgcn_fdot2(a, b, c, false);
#else
    return fmaf((float)a.x, (float)b.x, fmaf((float)a.y, (float)b.y, c));
#endif
}

__global__ __launch_bounds__(256, 3)
void xbilateral_kernel(const float* __restrict__ inp,
                       const float* __restrict__ alb,
                       const float* __restrict__ nrm,
                       const float* __restrict__ dep,
                       float* __restrict__ out)
{
    __shared__ uint2 sAD[HW2][HW2];  // f16 {a0,a1 | a2,dep} * sqrt(log2e/sigma)
    __shared__ uint2 sN [HW2][HW2];  // f16 {n0,n1 | n2,0}   * sqrt(log2e/sigma)
    __shared__ uint2 sI [HW2][HW2];  // f16 {i0,i1 | i2,1.0}

    const int tid = threadIdx.x;
    const int lx  = tid & 31;        // 0..31
    const int ly  = tid >> 5;        // 0..7
    const int bx0 = blockIdx.x * TW;
    const int by0 = blockIdx.y * TH;
    const int b   = blockIdx.z;

    const float kA = 12.01122406f;   // sqrt(1.44269504/0.01)
    const float kN = 3.79828255f;    // sqrt(1.44269504/0.1)  (also depth)

    const size_t plane = (size_t)HH * WW;
    const float* albB = alb + (size_t)b * 3 * plane;
    const float* nrmB = nrm + (size_t)b * 3 * plane;
    const float* inpB = inp + (size_t)b * 3 * plane;
    const float* depB = dep + (size_t)b * plane;

    // ---- stage halo tile (clamped coords, scaled f16) ----
    for (int idx = tid; idx < HW2 * HW2; idx += 256) {
        int r = idx / HW2;
        int c = idx - r * HW2;
        int gy = by0 + r - PAD; gy = min(max(gy, 0), HH - 1);
        int gx = bx0 + c - PAD; gx = min(max(gx, 0), WW - 1);
        size_t o = (size_t)gy * WW + gx;
        float a0 = albB[o] * kA, a1 = albB[plane + o] * kA, a2 = albB[2 * plane + o] * kA;
        float n0 = nrmB[o] * kN, n1 = nrmB[plane + o] * kN, n2 = nrmB[2 * plane + o] * kN;
        float d0 = depB[o] * kN;
        sAD[r][c] = make_uint2(pk2(a0, a1), pk2(a2, d0));
        sN [r][c] = make_uint2(pk2(n0, n1), pk2(n2, 0.f));
        float i0 = inpB[o], i1 = inpB[plane + o], i2 = inpB[2 * plane + o];
        sI [r][c] = make_uint2(pk2(i0, i1), pk2(i2, 1.f));
    }
    __syncthreads();

    // ---- per-thread: 4 vertically adjacent pixels, tile rows 4*ly + 0..3 ----
    const int py0 = 4 * ly;

    uint2 t0 = sAD[py0 + 0 + PAD][lx + PAD], u0 = sN[py0 + 0 + PAD][lx + PAD];
    uint2 t1 = sAD[py0 + 1 + PAD][lx + PAD], u1 = sN[py0 + 1 + PAD][lx + PAD];
    uint2 t2 = sAD[py0 + 2 + PAD][lx + PAD], u2 = sN[py0 + 2 + PAD][lx + PAD];
    uint2 t3 = sAD[py0 + 3 + PAD][lx + PAD], u3 = sN[py0 + 3 + PAD][lx + PAD];
    h2 cA0 = bch2(t0.x), cP0 = bch2(t0.y), cN0 = bch2(u0.x), cZ0 = bch2(u0.y);
    h2 cA1 = bch2(t1.x), cP1 = bch2(t1.y), cN1 = bch2(u1.x), cZ1 = bch2(u1.y);
    h2 cA2 = bch2(t2.x), cP2 = bch2(t2.y), cN2 = bch2(u2.x), cZ2 = bch2(u2.y);
    h2 cA3 = bch2(t3.x), cP3 = bch2(t3.y), cN3 = bch2(u3.x), cZ3 = bch2(u3.y);

    float4 a0 = make_float4(0.f, 0.f, 0.f, 0.f);
    float4 a1 = make_float4(0.f, 0.f, 0.f, 0.f);
    float4 a2 = make_float4(0.f, 0.f, 0.f, 0.f);
    float4 a3 = make_float4(0.f, 0.f, 0.f, 0.f);

#pragma unroll 1
    for (int t = 0; t < 14; ++t) {                 // window rows
        // kill-seed: out-of-window pixels get e >= 1e4 (never alive, w==0)
        float bk0 = ((unsigned)(t - 0) <= 10u) ? 0.f : BIGE;
        float bk1 = ((unsigned)(t - 1) <= 10u) ? 0.f : BIGE;
        float bk2 = ((unsigned)(t - 2) <= 10u) ? 0.f : BIGE;
        float bk3 = ((unsigned)(t - 3) <= 10u) ? 0.f : BIGE;

        const uint2* pAD = &sAD[py0 + t][lx];
        const uint2* pN  = &sN [py0 + t][lx];
        const uint2* pI  = &sI [py0 + t][lx];

#pragma unroll
        for (int dx = 0; dx < WIN; ++dx) {
            uint2 gad = pAD[dx];
            h2 g01 = bch2(gad.x), g2p = bch2(gad.y);

#define EAD(K)                                                                  \
            float e##K;                                                         \
            {                                                                   \
                h2 d01 = g01 - cA##K;                                           \
                h2 d2p = g2p - cP##K;                                           \
                e##K = fdot2(d01, d01, fdot2(d2p, d2p, bk##K));                 \
            }
            EAD(0) EAD(1) EAD(2) EAD(3)
#undef EAD
            float m = fminf(fminf(e0, e1), fminf(e2, e3));
            if (__any(m < T_CULL)) {
                uint2 gn = pN[dx];
                uint2 gi = pI[dx];
                h2 n01 = bch2(gn.x), n2z = bch2(gn.y);
                h2 i01 = bch2(gi.x), i2o = bch2(gi.y);
#define TAP(K)                                                                  \
                {                                                               \
                    h2 dn = n01 - cN##K;                                        \
                    h2 dz = n2z - cZ##K;                                        \
                    float e = fdot2(dn, dn, fdot2(dz, dz, e##K));               \
                    float w = __builtin_amdgcn_exp2f(-e);                       \
                    a##K.x = fmaf(w, (float)i01.x, a##K.x);                     \
                    a##K.y = fmaf(w, (float)i01.y, a##K.y);                     \
                    a##K.z = fmaf(w, (float)i2o.x, a##K.z);                     \
                    a##K.w = fmaf(w, (float)i2o.y, a##K.w);                     \
                }
                TAP(0) TAP(1) TAP(2) TAP(3)
#undef TAP
            }
        }
    }

    // ---- write out (guard H tail: grid y = ceil(720/32) = 23) ----
    const int ox = bx0 + lx;
    float* outB = out + (size_t)b * 3 * plane;
#define WOUT(K)                                                                 \
    {                                                                           \
        int oy = by0 + py0 + K;                                                 \
        if (oy < HH) {                                                          \
            float inv = 1.0f / fmaxf(a##K.w, 1e-10f);                           \
            size_t o = (size_t)oy * WW + ox;                                    \
            outB[o]             = a##K.x * inv;                                 \
            outB[plane + o]     = a##K.y * inv;                                 \
            outB[2 * plane + o] = a##K.z * inv;                                 \
        }                                                                       \
    }
    WOUT(0) WOUT(1) WOUT(2) WOUT(3)
#undef WOUT
}

extern "C" void kernel_launch(void* const* d_in, const int* in_sizes, int n_in,
                              void* d_out, int out_size, void* d_ws, size_t ws_size,
                              hipStream_t stream) {
    const float* inp = (const float*)d_in[0];
    const float* alb = (const float*)d_in[1];
    const float* nrm = (const float*)d_in[2];
    const float* dep = (const float*)d_in[3];
    // d_in[4] = win_size (always 11, compiled in)
    float* out = (float*)d_out;

    dim3 grid(WW / TW, (HH + TH - 1) / TH, 4);   // 40 x 23 x 4
    dim3 block(256);
    xbilateral_kernel<<<grid, block, 0, stream>>>(inp, alb, nrm, dep, out);
}

// Round 10
// 262.862 us; speedup vs baseline: 1.1280x; 1.0827x over previous
//
#include <hip/hip_runtime.h>
#include <math.h>

// Cross-bilateral filter, B=4, C=3, H=720, W=1280, WIN=11 (pad=5), f32.
//
// R10: OCCUPANCY experiment. All prior rounds: occ 21-42%, VALUBusy ~80%,
// dur 244-330 regardless of structure; best time correlated with highest
// occupancy (R3: 42.5% -> 244us). This kernel maximizes waves/CU:
//  - 16x16 tile, 1 px/thread: no ramp/kill/multi-pixel logic at all.
//  - halo 26x26, 28 B/cell: guide 8xf16 (uint4) + gg f32 + input 4xf16
//    (uint2) = 18.9 KB LDS -> 8 blocks/CU.
//  - __launch_bounds__(256, 8): cap 64 VGPR -> 32 waves/CU (100% occ).
//  - Tap math: f32 DOT-FORM (R8-proven, absmax 0.031): s = u_t.u_p - gg_t
//    - gg_p = -0.5||u_t - u_p||^2 EXACTLY (gg computed f32 from the
//    f16-ROUNDED u values; f16xf16 products are exact in f32).
//    7 channels via fmaf((float)f16,(float)f16,s) -> v_fma_mix_f32:
//    one slot per channel, no packed-f16 arithmetic anywhere.
//  - Per tap: 3 LDS loads (b128 guide, b32 gg, b64 input) + 1 sub + 7 mix
//    + exp2 + 4 mix-acc. wy rolled, dx unrolled (immediate offsets).

#define HH   720
#define WW   1280
#define PAD  5
#define WIN  11
#define TW   16
#define TH   16
#define HLO  26            // TW + 2*PAD

typedef _Float16 h2 __attribute__((ext_vector_type(2)));

__device__ __forceinline__ unsigned pkh(_Float16 a, _Float16 b) {
    unsigned lo = __builtin_bit_cast(unsigned short, a);
    unsigned hi = __builtin_bit_cast(unsigned short, b);
    return lo | (hi << 16);
}
__device__ __forceinline__ h2 bch2(unsigned u) { return __builtin_bit_cast(h2, u); }

__global__ __launch_bounds__(256, 8)
void xbilateral_kernel(const float* __restrict__ inp,
                       const float* __restrict__ alb,
                       const float* __restrict__ nrm,
                       const float* __restrict__ dep,
                       float* __restrict__ out)
{
    __shared__ uint4 sG [HLO][HLO];  // 8 x f16: sqrt(2*log2e/sigma)-scaled {a0,a1,a2,d, n0,n1,n2,0}
    __shared__ float sGG[HLO][HLO];  // f32 gg = 0.5*u.u (from f16-ROUNDED u)
    __shared__ uint2 sI [HLO][HLO];  // f16 {i0,i1 | i2,1.0}

    const int tid = threadIdx.x;
    const int lx  = tid & 15;        // 0..15
    const int ly  = tid >> 4;        // 0..15
    const int bx0 = blockIdx.x * TW;
    const int by0 = blockIdx.y * TH;
    const int b   = blockIdx.z;

    const float kA2 = 16.98653137f;  // sqrt(2*1.44269504/0.01)
    const float kN2 = 5.37154913f;   // sqrt(2*1.44269504/0.1)

    const size_t plane = (size_t)HH * WW;
    const float* albB = alb + (size_t)b * 3 * plane;
    const float* nrmB = nrm + (size_t)b * 3 * plane;
    const float* inpB = inp + (size_t)b * 3 * plane;
    const float* depB = dep + (size_t)b * plane;

    // ---- stage halo (clamped coords). gg from the ROUNDED f16 values. ----
    for (int idx = tid; idx < HLO * HLO; idx += 256) {
        int r = idx / HLO;
        int c = idx - r * HLO;
        int gy = by0 + r - PAD; gy = min(max(gy, 0), HH - 1);
        int gx = bx0 + c - PAD; gx = min(max(gx, 0), WW - 1);
        size_t o = (size_t)gy * WW + gx;
        _Float16 u0 = (_Float16)(albB[o] * kA2);
        _Float16 u1 = (_Float16)(albB[plane + o] * kA2);
        _Float16 u2 = (_Float16)(albB[2 * plane + o] * kA2);
        _Float16 u3 = (_Float16)(depB[o] * kN2);
        _Float16 u4 = (_Float16)(nrmB[o] * kN2);
        _Float16 u5 = (_Float16)(nrmB[plane + o] * kN2);
        _Float16 u6 = (_Float16)(nrmB[2 * plane + o] * kN2);
        float f0 = (float)u0, f1 = (float)u1, f2 = (float)u2, f3 = (float)u3;
        float f4 = (float)u4, f5 = (float)u5, f6 = (float)u6;
        sG[r][c]  = make_uint4(pkh(u0, u1), pkh(u2, u3), pkh(u4, u5), pkh(u6, (_Float16)0.f));
        sGG[r][c] = 0.5f * (f0 * f0 + f1 * f1 + f2 * f2 + f3 * f3 +
                            f4 * f4 + f5 * f5 + f6 * f6);
        _Float16 i0 = (_Float16)inpB[o];
        _Float16 i1 = (_Float16)inpB[plane + o];
        _Float16 i2 = (_Float16)inpB[2 * plane + o];
        sI[r][c] = make_uint2(pkh(i0, i1), pkh(i2, (_Float16)1.f));
    }
    __syncthreads();

    // ---- one pixel per thread ----
    uint4 gc = sG[ly + PAD][lx + PAD];
    h2 c0 = bch2(gc.x), c1 = bch2(gc.y), c2 = bch2(gc.z), c3 = bch2(gc.w);
    float nggp = -sGG[ly + PAD][lx + PAD];

    float4 acc = make_float4(0.f, 0.f, 0.f, 0.f);

#pragma unroll 1
    for (int wy = 0; wy < WIN; ++wy) {
        const uint4* rg  = &sG [ly + wy][lx];
        const float* rgg = &sGG[ly + wy][lx];
        const uint2* ri  = &sI [ly + wy][lx];
#pragma unroll
        for (int dx = 0; dx < WIN; ++dx) {
            uint4 g = rg[dx];
            float s = nggp - rgg[dx];
            uint2 t = ri[dx];
            h2 g0 = bch2(g.x), g1 = bch2(g.y), g2 = bch2(g.z), g3 = bch2(g.w);
            s = fmaf((float)g0.x, (float)c0.x, s);   // v_fma_mix_f32 x7
            s = fmaf((float)g0.y, (float)c0.y, s);
            s = fmaf((float)g1.x, (float)c1.x, s);
            s = fmaf((float)g1.y, (float)c1.y, s);
            s = fmaf((float)g2.x, (float)c2.x, s);
            s = fmaf((float)g2.y, (float)c2.y, s);
            s = fmaf((float)g3.x, (float)c3.x, s);
            float w = __builtin_amdgcn_exp2f(s);
            h2 i01 = bch2(t.x), i2o = bch2(t.y);
            acc.x = fmaf(w, (float)i01.x, acc.x);
            acc.y = fmaf(w, (float)i01.y, acc.y);
            acc.z = fmaf(w, (float)i2o.x, acc.z);
            acc.w += w;
        }
    }

    // ---- write out (720/16 = 45, 1280/16 = 80: exact, no guards) ----
    const int ox = bx0 + lx;
    const int oy = by0 + ly;
    float* outB = out + (size_t)b * 3 * plane;
    float inv = 1.0f / fmaxf(acc.w, 1e-10f);
    size_t o = (size_t)oy * WW + ox;
    outB[o]             = acc.x * inv;
    outB[plane + o]     = acc.y * inv;
    outB[2 * plane + o] = acc.z * inv;
}

extern "C" void kernel_launch(void* const* d_in, const int* in_sizes, int n_in,
                              void* d_out, int out_size, void* d_ws, size_t ws_size,
                              hipStream_t stream) {
    const float* inp = (const float*)d_in[0];
    const float* alb = (const float*)d_in[1];
    const float* nrm = (const float*)d_in[2];
    const float* dep = (const float*)d_in[3];
    // d_in[4] = win_size (always 11, compiled in)
    float* out = (float*)d_out;

    dim3 grid(WW / TW, HH / TH, 4);   // 80 x 45 x 4
    dim3 block(256);
    xbilateral_kernel<<<grid, block, 0, stream>>>(inp, alb, nrm, dep, out);
}

// Round 11
// 257.197 us; speedup vs baseline: 1.1528x; 1.0220x over previous
//
#include <hip/hip_runtime.h>
#include <math.h>

// Cross-bilateral filter, B=4, C=3, H=720, W=1280, WIN=11 (pad=5), f32.
//
// R11 = R10's accuracy-proven f32 dot-form/fma_mix math (absmax 0.03125)
//       on R3's conflict-free geometry, 3 px/thread, no launch-bound choke.
//  - Geometry: 32x24 tile, block 32x8, 42-col LDS rows, 32-lane row reads
//    (R1/R3/R5/R8/R9 all measured SQ_LDS_BANK_CONFLICT == 0 with this).
//    R10's 26-col/16-lane layout hit 4.3e7 conflicts; its (256,8) bound
//    forced VGPR=32 -> 296MB scratch. Both defects fixed here.
//  - 3 vertically adjacent px/thread (rows 3ly..3ly+2): 13 window rows
//    serve 3x11 row-taps -> 47.7 cell-reads/px (R3: 132).
//  - Cell: guide 8xf16 uint4 {a0,a1|a2,d|n0,n1|n2,0} scaled by
//    sqrt(2*log2e/sigma); gg f32 (separate array, computed from the f16-
//    ROUNDED values: s = u.c - ggt - ggc == -0.5||u_t-u_c||^2 exactly);
//    input f16 uint2 {i0,i1|i2,1.0}. 28 B/cell, 39 KB -> 4 blocks/CU.
//  - Per tap: s = (negc_k - bk_k_row) - ggt (1 sub; kill-seed folded into
//    the per-row scalar), 7x v_fma_mix_f32, exp2, 3x mix-acc + 1 add.
//  - dx fully unrolled; wy rolled; all hot values named scalars.

#define HH   720
#define WW   1280
#define PAD  5
#define WIN  11
#define TW   32
#define TH   24
#define HR   34            // halo rows = TH + 2*PAD
#define HC   42            // halo cols = TW + 2*PAD
#define BIGE 1.0e4f

typedef _Float16 h2 __attribute__((ext_vector_type(2)));

__device__ __forceinline__ unsigned pkh(_Float16 a, _Float16 b) {
    unsigned lo = __builtin_bit_cast(unsigned short, a);
    unsigned hi = __builtin_bit_cast(unsigned short, b);
    return lo | (hi << 16);
}
__device__ __forceinline__ h2 bch2(unsigned u) { return __builtin_bit_cast(h2, u); }

__global__ __launch_bounds__(256, 4)
void xbilateral_kernel(const float* __restrict__ inp,
                       const float* __restrict__ alb,
                       const float* __restrict__ nrm,
                       const float* __restrict__ dep,
                       float* __restrict__ out)
{
    __shared__ uint4 sG [HR][HC];  // 8 x f16 scaled {a0,a1, a2,d, n0,n1, n2,0}
    __shared__ float sGG[HR][HC];  // f32 gg = 0.5*u.u (from f16-rounded u)
    __shared__ uint2 sI [HR][HC];  // f16 {i0,i1 | i2,1.0}

    const int tid = threadIdx.x;
    const int lx  = tid & 31;      // 0..31
    const int ly  = tid >> 5;      // 0..7
    const int bx0 = blockIdx.x * TW;
    const int by0 = blockIdx.y * TH;
    const int b   = blockIdx.z;

    const float kA2 = 16.98653137f;  // sqrt(2*1.44269504/0.01)
    const float kN2 = 5.37154913f;   // sqrt(2*1.44269504/0.1)

    const size_t plane = (size_t)HH * WW;
    const float* albB = alb + (size_t)b * 3 * plane;
    const float* nrmB = nrm + (size_t)b * 3 * plane;
    const float* inpB = inp + (size_t)b * 3 * plane;
    const float* depB = dep + (size_t)b * plane;

    // ---- stage halo (clamped coords); gg from the ROUNDED f16 values ----
    for (int idx = tid; idx < HR * HC; idx += 256) {
        int r = idx / HC;
        int c = idx - r * HC;
        int gy = by0 + r - PAD; gy = min(max(gy, 0), HH - 1);
        int gx = bx0 + c - PAD; gx = min(max(gx, 0), WW - 1);
        size_t o = (size_t)gy * WW + gx;
        _Float16 u0 = (_Float16)(albB[o] * kA2);
        _Float16 u1 = (_Float16)(albB[plane + o] * kA2);
        _Float16 u2 = (_Float16)(albB[2 * plane + o] * kA2);
        _Float16 u3 = (_Float16)(depB[o] * kN2);
        _Float16 u4 = (_Float16)(nrmB[o] * kN2);
        _Float16 u5 = (_Float16)(nrmB[plane + o] * kN2);
        _Float16 u6 = (_Float16)(nrmB[2 * plane + o] * kN2);
        float f0 = (float)u0, f1 = (float)u1, f2 = (float)u2, f3 = (float)u3;
        float f4 = (float)u4, f5 = (float)u5, f6 = (float)u6;
        sG[r][c]  = make_uint4(pkh(u0, u1), pkh(u2, u3), pkh(u4, u5), pkh(u6, (_Float16)0.f));
        sGG[r][c] = 0.5f * (f0 * f0 + f1 * f1 + f2 * f2 + f3 * f3 +
                            f4 * f4 + f5 * f5 + f6 * f6);
        _Float16 i0 = (_Float16)inpB[o];
        _Float16 i1 = (_Float16)inpB[plane + o];
        _Float16 i2 = (_Float16)inpB[2 * plane + o];
        sI[r][c] = make_uint2(pkh(i0, i1), pkh(i2, (_Float16)1.f));
    }
    __syncthreads();

    // ---- 3 vertically adjacent pixels per thread: tile rows 3ly..3ly+2 ----
    const int py0 = 3 * ly;

    uint4 gA = sG[py0 + 0 + PAD][lx + PAD];
    uint4 gB = sG[py0 + 1 + PAD][lx + PAD];
    uint4 gC = sG[py0 + 2 + PAD][lx + PAD];
    h2 cA0 = bch2(gA.x), cA1 = bch2(gA.y), cA2 = bch2(gA.z), cA3 = bch2(gA.w);
    h2 cB0 = bch2(gB.x), cB1 = bch2(gB.y), cB2 = bch2(gB.z), cB3 = bch2(gB.w);
    h2 cC0 = bch2(gC.x), cC1 = bch2(gC.y), cC2 = bch2(gC.z), cC3 = bch2(gC.w);
    float ncA = -sGG[py0 + 0 + PAD][lx + PAD];
    float ncB = -sGG[py0 + 1 + PAD][lx + PAD];
    float ncC = -sGG[py0 + 2 + PAD][lx + PAD];

    float4 aA = make_float4(0.f, 0.f, 0.f, 0.f);
    float4 aB = make_float4(0.f, 0.f, 0.f, 0.f);
    float4 aC = make_float4(0.f, 0.f, 0.f, 0.f);

#pragma unroll 1
    for (int wy = 0; wy < 13; ++wy) {          // window-row union for 3 px
        // fold the out-of-window kill into the per-row seed (w -> exp2(-1e4) = 0)
        float baseA = ncA - ((wy <= 10) ? 0.f : BIGE);            // A: wy 0..10
        float baseB = ncB - (((unsigned)(wy - 1) <= 10u) ? 0.f : BIGE); // B: 1..11
        float baseC = ncC - ((wy >= 2) ? 0.f : BIGE);             // C: 2..12

        const uint4* pG  = &sG [py0 + wy][lx];
        const float* pGG = &sGG[py0 + wy][lx];
        const uint2* pI  = &sI [py0 + wy][lx];

#pragma unroll
        for (int dx = 0; dx < WIN; ++dx) {
            uint4 g  = pG[dx];
            float gt = pGG[dx];
            uint2 ti = pI[dx];
            h2 g0 = bch2(g.x), g1 = bch2(g.y), g2 = bch2(g.z), g3 = bch2(g.w);
            h2 i01 = bch2(ti.x), i2o = bch2(ti.y);

#define TAP(S, C0, C1, C2, C3, ACC)                                            \
            {                                                                   \
                float s = (S) - gt;                                             \
                s = fmaf((float)g0.x, (float)C0.x, s);                          \
                s = fmaf((float)g0.y, (float)C0.y, s);                          \
                s = fmaf((float)g1.x, (float)C1.x, s);                          \
                s = fmaf((float)g1.y, (float)C1.y, s);                          \
                s = fmaf((float)g2.x, (float)C2.x, s);                          \
                s = fmaf((float)g2.y, (float)C2.y, s);                          \
                s = fmaf((float)g3.x, (float)C3.x, s);                          \
                float w = __builtin_amdgcn_exp2f(s);                            \
                ACC.x = fmaf(w, (float)i01.x, ACC.x);                           \
                ACC.y = fmaf(w, (float)i01.y, ACC.y);                           \
                ACC.z = fmaf(w, (float)i2o.x, ACC.z);                           \
                ACC.w += w;                                                     \
            }
            TAP(baseA, cA0, cA1, cA2, cA3, aA)
            TAP(baseB, cB0, cB1, cB2, cB3, aB)
            TAP(baseC, cC0, cC1, cC2, cC3, aC)
#undef TAP
        }
    }

    // ---- write out (720 = 30*24, 1280 = 40*32: exact, no guards) ----
    const int ox = bx0 + lx;
    float* outB = out + (size_t)b * 3 * plane;
#define WOUT(K, ACC)                                                            \
    {                                                                           \
        int oy = by0 + py0 + K;                                                 \
        float inv = 1.0f / fmaxf(ACC.w, 1e-10f);                                \
        size_t o = (size_t)oy * WW + ox;                                        \
        outB[o]             = ACC.x * inv;                                      \
        outB[plane + o]     = ACC.y * inv;                                      \
        outB[2 * plane + o] = ACC.z * inv;                                      \
    }
    WOUT(0, aA) WOUT(1, aB) WOUT(2, aC)
#undef WOUT
}

extern "C" void kernel_launch(void* const* d_in, const int* in_sizes, int n_in,
                              void* d_out, int out_size, void* d_ws, size_t ws_size,
                              hipStream_t stream) {
    const float* inp = (const float*)d_in[0];
    const float* alb = (const float*)d_in[1];
    const float* nrm = (const float*)d_in[2];
    const float* dep = (const float*)d_in[3];
    // d_in[4] = win_size (always 11, compiled in)
    float* out = (float*)d_out;

    dim3 grid(WW / TW, HH / TH, 4);   // 40 x 30 x 4
    dim3 block(256);
    xbilateral_kernel<<<grid, block, 0, stream>>>(inp, alb, nrm, dep, out);
}